// Round 7
// baseline (103.311 us; speedup 1.0000x reference)
//
#include <hip/hip_runtime.h>
#include <cstdint>
#include <cstddef>

// Problem constants (from reference)
#define B_SZ   512
#define DIN    256
#define DOUT   256
#define KNOTS  64
#define NK     63                 // intervals = KNOTS-1
#define HSTEP  (4.0f / 63.0f)
#define INV_H  15.75f             // exact in f32

// XCD-affine slicing of the input dimension
#define NSLICE 8                  // = number of XCDs
#define ISLICE (DIN / NSLICE)     // 32 input dims -> 3.94 MiB table slice (fits 4 MiB L2)
#define SPB    4                  // samples per forward block

// build geometry: 1024 blocks = 256 i x 4 o-chunks of 64
#define OCW    64                 // o-chunk width per build block
#define LSTR   67                 // LDS row stride (floats): 67%32=3 -> 2-way banks (free)

typedef _Float16 h2f __attribute__((ext_vector_type(2)));

// Per-interval table entry: {y0, y1-y0, h*m0, h*m1} as 4 x f16 = 8 B.
struct __align__(8) Ent { h2f ydy; h2f hmm; };

// Per-(b,i) record: table byte offset + hermite weights {1,h01} {h10,h11}.
struct __align__(16) Rec { int off; h2f w01; h2f w23; int pad; };

static_assert(sizeof(Ent) == 8,  "Ent must be 8 bytes");
static_assert(sizeof(Rec) == 16, "Rec must be 16 bytes");

#if defined(__has_builtin)
#  if __has_builtin(__builtin_amdgcn_fdot2)
#    define HAVE_FDOT2 1
#  endif
#endif

static __device__ __forceinline__ float dot2acc(h2f a, h2f b, float acc) {
#ifdef HAVE_FDOT2
    return __builtin_amdgcn_fdot2(a, b, acc, false);
#else
    return acc + (float)a.x * (float)b.x + (float)a.y * (float)b.y;
#endif
}

// ---- PCHIP slope helpers (reference semantics, f32 exact) ----
static __device__ __forceinline__ float pchip_edge(float dA, float dB) {
    float m = 0.5f * (3.0f * dA - dB);
    if (m * dA <= 0.0f) {
        m = 0.0f;
    } else if (dA * dB < 0.0f && fabsf(m) > 3.0f * fabsf(dA)) {
        m = 3.0f * dA;
    }
    return m;
}

static __device__ __forceinline__ float pchip_inner(float d0, float d1) {
    if (d0 * d1 > 0.0f) {
        float denom = d0 + d1;
        if (fabsf(denom) < 1e-12f) return 0.0f;
        return 2.0f * d0 * d1 / denom;
    }
    return 0.0f;
}

// ---- Kernel 1: build per-interval table + init out = bias (REWRITTEN) ----
// Grid 1024 = 256 i x 4 o-chunks. bid&7 = slice(i) -> table lines born in the
// XCD L2 that kan_forward (slice = bid&7) reads them from.
// Phase A: stage 64 contiguous (i,o)-rows (16 KB) into LDS, coalesced float4.
// Phase B: 4 threads per row, each computes 15-16 entries from a 19-float
// halo window. 4 blocks/CU (17 KB LDS) -> 16 waves/CU vs the old 4.
__global__ __launch_bounds__(256) void build_coef(const float* __restrict__ y,
                                                  Ent* __restrict__ C,
                                                  const float* __restrict__ bias,
                                                  float* __restrict__ out) {
    __shared__ float ly[OCW * LSTR];      // 17,152 B

    const int bid   = blockIdx.x;
    const int slice = bid & 7;
    const int jdim  = (bid >> 3) & 31;
    const int i     = slice * ISLICE + jdim;   // input dim, XCD-affine
    const int oc    = bid >> 8;                // o-chunk 0..3
    const int o0    = oc * OCW;
    const int t     = threadIdx.x;

    // out = bias init: first 256 blocks write one float2 per thread.
    if (bid < 256) {
        int t2 = bid * 256 + t;
        int ob = (t * 2) & (DOUT - 1);
        float2 bv;
        bv.x = bias[ob];
        bv.y = bias[ob + 1];
        ((float2*)out)[t2] = bv;
    }

    // ---- Phase A: coalesced stage of 64 rows x 64 knots ----
    const float4* src = (const float4*)(y + ((size_t)i * DOUT + o0) * KNOTS);
#pragma unroll
    for (int z = 0; z < 4; ++z) {
        int f = t + 256 * z;              // float4 index 0..1023 (contiguous 16 KB)
        float4 v = src[f];
        int row = f >> 4;
        int kq  = (f & 15) * 4;
        float* dst = &ly[row * LSTR + kq];
        dst[0] = v.x; dst[1] = v.y; dst[2] = v.z; dst[3] = v.w;
    }
    __syncthreads();

    // ---- Phase B: 4 threads/row, 16-entry strips with halo ----
    const int r  = t >> 2;                // row 0..63 -> o = o0 + r
    const int q  = t & 3;                 // strip 0..3
    const int k0 = q * 16;
    const int o  = o0 + r;
    const float* rowp = &ly[r * LSTR];

    float ys[19];                         // y[k0-1 .. k0+17], clamped
#pragma unroll
    for (int u = 0; u < 19; ++u) {
        int kk = k0 - 1 + u;
        kk = kk < 0 ? 0 : (kk > KNOTS - 1 ? KNOTS - 1 : kk);
        ys[u] = rowp[kk];
    }
    float dd[18];                         // dd[u] = d[k0-1+u]; clamp dups -> 0, unused
#pragma unroll
    for (int u = 0; u < 18; ++u) dd[u] = (ys[u + 1] - ys[u]) * INV_H;

    const int cnt = (q == 3) ? 15 : 16;   // strip 3 ends at k=62 (NK-1)
    Ent* outp = C + ((size_t)i * NK + k0) * DOUT + o;
#pragma unroll
    for (int n = 0; n < 16; ++n) {
        if (n < cnt) {
            const int k   = k0 + n;
            float d_m1 = dd[n];           // d[k-1] (0-dup at k=0, overwritten)
            float d_0  = dd[n + 1];       // d[k]
            float d_p1 = dd[n + 2];       // d[k+1] (0-dup at k=62, overwritten)
            float mk  = pchip_inner(d_m1, d_0);
            if (k == 0)      mk  = pchip_edge(d_0, d_p1);
            float mk1 = pchip_inner(d_0, d_p1);
            if (k == NK - 1) mk1 = pchip_edge(d_0, d_m1);
            float y0 = ys[n + 1];
            float y1 = ys[n + 2];
            Ent e;
            e.ydy.x = (_Float16)y0;
            e.ydy.y = (_Float16)(y1 - y0);
            e.hmm.x = (_Float16)(HSTEP * mk);
            e.hmm.y = (_Float16)(HSTEP * mk1);
            outp[(size_t)n * DOUT] = e;
        }
    }
}

// ---- Kernel 2: forward pass — UNCHANGED from round 6 (known-good) ----
// grid = (B/SPB) * NSLICE = 1024 blocks of 1024 threads (4 samples x 256 o).
// slice = bid%8 pins each block's 3.94 MiB table slice to one XCD's L2.
// Inner loop per term: broadcast ds_read_b128 (record), v_add_u32,
// global_load_dwordx2 (L2-hit), 2x v_dot2_f32_f16 into an f32 accumulator.
__global__ __launch_bounds__(1024) void kan_forward(const float* __restrict__ x,
                                                    const Ent* __restrict__ C,
                                                    float* __restrict__ out) {
    __shared__ Rec recs[SPB * ISLICE];    // 128 records x 16 B = 2 KB

    const int bid   = blockIdx.x;
    const int slice = bid & (NSLICE - 1);
    const int chunk = bid >> 3;
    const int tid   = threadIdx.x;

    if (tid < SPB * ISLICE) {             // 128 threads stage the records
        const int s = tid >> 5;
        const int j = tid & (ISLICE - 1);
        const int b = chunk * SPB + s;
        const int i = slice * ISLICE + j;
        float xv = x[b * DIN + i];
        float xc = fminf(fmaxf(xv, -2.0f), 2.0f);
        float tv = (xc + 2.0f) * INV_H;
        int k = (int)tv;                  // tv >= 0
        k = k > NK - 1 ? NK - 1 : k;
        float u   = tv - (float)k;
        float u2  = u * u;
        float um1 = u - 1.0f;
        float c1  = u2 * (3.0f - 2.0f * u);   // h01
        float c2  = u * um1 * um1;            // h10
        float c3  = u2 * um1;                 // h11
        Rec r;
        r.off   = (i * NK + k) << 11;         // *DOUT*sizeof(Ent) = *2048 bytes
        r.w01.x = (_Float16)1.0f;
        r.w01.y = (_Float16)c1;
        r.w23.x = (_Float16)c2;
        r.w23.y = (_Float16)c3;
        r.pad   = 0;
        recs[tid] = r;
    }
    __syncthreads();

    const int s  = tid >> 8;              // sample 0..3
    const int o  = tid & (DOUT - 1);
    const unsigned ob = (unsigned)o * (unsigned)sizeof(Ent);  // loop-invariant
    const char* base = (const char*)C;

    float acc = 0.0f;
#pragma unroll 8
    for (int j = 0; j < ISLICE; ++j) {
        Rec r = recs[s * ISLICE + j];                       // broadcast b128
        const Ent* e = (const Ent*)(base + ((unsigned)r.off + ob));
        Ent v = *e;                                         // 8 B, L2-resident
        acc = dot2acc(v.ydy, r.w01, acc);                   // y0*1 + dy*h01
        acc = dot2acc(v.hmm, r.w23, acc);                   // hm0*h10 + hm1*h11
    }
    atomicAdd(&out[(chunk * SPB + s) * DOUT + o], acc);
}

// ---- Fallback: no-workspace path (only if ws_size is too small) ----
__global__ __launch_bounds__(256) void kan_naive(const float* __restrict__ x,
                                                 const float* __restrict__ y,
                                                 const float* __restrict__ bias,
                                                 float* __restrict__ out) {
    __shared__ int   sk[DIN];
    __shared__ float su[DIN];

    const int b   = blockIdx.x;
    const int tid = threadIdx.x;
    const float h = HSTEP;

    {
        float xv = x[b * DIN + tid];
        float xc = fminf(fmaxf(xv, -2.0f), 2.0f);
        float t  = (xc + 2.0f) / h;
        int k = (int)floorf(t);
        k = k < 0 ? 0 : (k > NK - 1 ? NK - 1 : k);
        sk[tid] = k;
        su[tid] = t - (float)k;
    }
    __syncthreads();

    const int o = tid;
    float acc = 0.0f;
    for (int i = 0; i < DIN; ++i) {
        int   k = sk[i];
        float u = su[i];
        const float* r = y + ((size_t)i * DOUT + o) * KNOTS;
        float ym1 = r[k > 0 ? k - 1 : 0];
        float y0  = r[k];
        float y1  = r[k + 1];
        float y2  = r[k < NK - 1 ? k + 2 : KNOTS - 1];
        float dm1 = (y0 - ym1) / h;
        float d0  = (y1 - y0) / h;
        float d1  = (y2 - y1) / h;
        float mk  = (k == 0)      ? pchip_edge(d0, d1)  : pchip_inner(dm1, d0);
        float mk1 = (k == NK - 1) ? pchip_edge(d0, dm1) : pchip_inner(d0, d1);
        float hm0 = h * mk, hm1 = h * mk1;
        float dy = y1 - y0;
        float c2 = 3.0f * dy - 2.0f * hm0 - hm1;
        float c3 = hm0 + hm1 - 2.0f * dy;
        acc += fmaf(u, fmaf(u, fmaf(u, c3, c2), hm0), y0);
    }
    out[b * DOUT + o] = acc + bias[o];
}

extern "C" void kernel_launch(void* const* d_in, const int* in_sizes, int n_in,
                              void* d_out, int out_size, void* d_ws, size_t ws_size,
                              hipStream_t stream) {
    const float* x    = (const float*)d_in[0];   // (B, DIN)
    const float* y    = (const float*)d_in[1];   // (DIN, DOUT, KNOTS)
    const float* bias = (const float*)d_in[2];   // (DOUT,)
    float* out        = (float*)d_out;           // (B, DOUT)

    const size_t need = (size_t)DIN * NK * DOUT * sizeof(Ent); // ~33 MB

    if (ws_size >= need) {
        Ent* C = (Ent*)d_ws;
        build_coef<<<dim3(DIN * (DOUT / OCW)), dim3(256), 0, stream>>>(y, C, bias, out);
        kan_forward<<<dim3((B_SZ / SPB) * NSLICE), dim3(1024), 0, stream>>>(x, C, out);
    } else {
        kan_naive<<<dim3(B_SZ), dim3(256), 0, stream>>>(x, y, bias, out);
    }
}